// Round 16
// baseline (59.193 us; speedup 1.0000x reference)
//
#include <hip/hip_runtime.h>

#define TT 1024
#define LL 64
#define BB 256               // batch
#define WARM 8               // warm-up steps (contraction <= 0.462/step)
#define NCHAIN 8192          // chains = pieces slots (4096 waves x 2)
#define LOG2E 1.44269504088896340736f
#define LN2   0.69314718055994530942f

typedef __fp16 half2v __attribute__((ext_vector_type(2)));
__device__ __forceinline__ half2v int_as_h2(int x) { union { int i; half2v h; } u; u.i = x; return u.h; }
__device__ __forceinline__ int h2_as_int(half2v x) { union { int i; half2v h; } u; u.h = x; return u.i; }

// TWO INTERLEAVED CHAINS PER WAVE. Pre-kernel: W = sum work_b
// (work_b = max(slen_b-1,1)), K = ceil(W/(NCHAIN-BB)) (so total pieces
// P = sum ceil(work_b/K) <= NCHAIN), prefix-sum piece counts -> meta.
// Pieces NEVER cross sequence boundaries: piece p of seq b covers
// t in [1+idx*K, min(+K, slen)). Wave wid runs pieces 2wid and 2wid+1
// with their steps interleaved instruction-by-instruction (chain A stalls
// hide under chain B's issue -> 8 independent chains/SIMD at 4 waves/SIMD).
// Loop runs N = max(stepsA, stepsB) rounded up to x4 with NO per-step
// guards; overshoot steps run on clamped rows after A_out is measured
// (harmless). Warm-start max(1, lo-WARM): positive transfer operator,
// Hilbert diameter of E=exp(trans) <= 2 -> contraction tanh(0.5)=0.462;
// delta = A(u@hi-1 post-step) - A(u@lo-1) telescopes to log_norm per seq
// (lo==1 pieces exact, A_in=0). slen=1: zero-step piece measuring
// logsumexp(logits[0]) at init. Each piece scores its own t-range.
//
// Step (round 13 numerics + round 15 DPP pack, no LDS anywhere):
//   g = exp2(ring_raw * LOG2E)            (ring value 4 steps old: off-chain)
//   s_j = sum_m pair_m(u) . ej[m]          32 readlane(even) + 32 fdot2
//   v = s * g;  renorm by exact pow-2 of v_0 (readfirstlane exponent), C += e
//   pack: un = shfl_xor(u,1) (DPP) + cvt_pkrtz -> even lane 2k = (u_2k,u_2k+1)

__global__ __launch_bounds__(256) void crf_prefix_kernel(
    const int* __restrict__ seq_lens, int* __restrict__ meta)
{
    __shared__ int sbuf[BB];
    const int tid = threadIdx.x;
    const int sl = seq_lens[tid];
    const int work = (sl > 1) ? (sl - 1) : 1;
    sbuf[tid] = work;
    __syncthreads();
    for (int off = 1; off < BB; off <<= 1) {
        int v = (tid >= off) ? sbuf[tid - off] : 0;
        __syncthreads();
        sbuf[tid] += v;
        __syncthreads();
    }
    const int W = sbuf[BB - 1];
    const int K = (W + (NCHAIN - BB) - 1) / (NCHAIN - BB);
    __syncthreads();
    sbuf[tid] = (work + K - 1) / K;       // pieces for seq tid
    __syncthreads();
    for (int off = 1; off < BB; off <<= 1) {
        int v = (tid >= off) ? sbuf[tid - off] : 0;
        __syncthreads();
        sbuf[tid] += v;
        __syncthreads();
    }
    meta[tid + 1] = sbuf[tid];
    if (tid == 0) { meta[0] = 0; meta[BB + 1] = K; }   // P = meta[BB]
}

#define PLD2(S, I) ((size_t)((((S) + (I)) < TT) ? ((S) + (I)) : (TT - 1)) * LL)

#define MEAS(X, OUT) { \
    float us_ = u##X; \
    _Pragma("unroll") \
    for (int off_ = 32; off_; off_ >>= 1) us_ += __shfl_xor(us_, off_, 64); \
    OUT = ((float)C##X + __builtin_amdgcn_logf(us_)) * LN2; \
}

#define PACKD(X) { \
    float un_ = __shfl_xor(u##X, 1, 64); \
    upk##X = h2_as_int(__builtin_amdgcn_cvt_pkrtz(u##X, un_)); \
}

#define SETUP(X, PIDX) { \
    const int p_ = (PIDX); \
    act##X = (p_ < P); \
    int b_ = 0, lo_ = 1; \
    if (act##X) { \
        int blo_ = 0, bhi_ = BB; \
        while (bhi_ - blo_ > 1) { int mid_ = (blo_ + bhi_) >> 1; \
            if (meta[mid_] <= p_) blo_ = mid_; else bhi_ = mid_; } \
        b_ = blo_; \
        lo_ = 1 + (p_ - meta[b_]) * K; \
    } \
    const int slen_ = seq_lens[b_]; \
    const float* lg_ = logits + (size_t)b_ * TT * LL; \
    const int* lab_ = labels + b_ * TT; \
    col##X = lg_ + lane; \
    hi##X = act##X ? ((lo_ + K < slen_) ? (lo_ + K) : slen_) : 0; \
    sc##X = 0.f; \
    if (act##X) { \
        int units_ = hi##X - lo_; \
        int t0_ = lo_ + lane; \
        if (lane < units_) { \
            int l1_ = lab_[t0_]; \
            sc##X = lg_[(size_t)t0_ * LL + l1_] + trans[lab_[t0_ - 1] * LL + l1_]; \
        } \
        if (lo_ == 1 && lane == 0) sc##X += lg_[lab_[0]]; \
        _Pragma("unroll") \
        for (int off_ = 32; off_; off_ >>= 1) sc##X += __shfl_xor(sc##X, off_, 64); \
    } \
    const int start_ = (lo_ - WARM > 1) ? (lo_ - WARM) : 1; \
    lo1##X = (lo_ > 1) ? (lo_ - 1) : -1; \
    steps##X = act##X ? (hi##X - start_) : 0; \
    t##X = start_; \
    C##X = 0; \
    u##X = __builtin_amdgcn_exp2f(col##X[(size_t)(start_ - 1) * LL] * LOG2E); \
    PACKD(X); \
    if (act##X && steps##X == 0) MEAS(X, A_out##X); \
    fr##X##0 = col##X[PLD2(start_, 0)]; \
    fr##X##1 = col##X[PLD2(start_, 1)]; \
    fr##X##2 = col##X[PLD2(start_, 2)]; \
    fr##X##3 = col##X[PLD2(start_, 3)]; \
}

#define STEP1(X, I) { \
    float g_ = __builtin_amdgcn_exp2f(fr##X##I * LOG2E); \
    int nr_ = t##X + 4; nr_ = (nr_ < TT) ? nr_ : (TT - 1); \
    fr##X##I = col##X[(size_t)nr_ * LL]; \
    float a1_ = 0.f, a2_ = 0.f, a3_ = 0.f, a4_ = 0.f; \
    _Pragma("unroll") \
    for (int m_ = 0; m_ < 32; m_ += 4) { \
        int q0_ = __builtin_amdgcn_readlane(upk##X, 2 * m_); \
        int q1_ = __builtin_amdgcn_readlane(upk##X, 2 * m_ + 2); \
        int q2_ = __builtin_amdgcn_readlane(upk##X, 2 * m_ + 4); \
        int q3_ = __builtin_amdgcn_readlane(upk##X, 2 * m_ + 6); \
        a1_ = __builtin_amdgcn_fdot2(int_as_h2(q0_), int_as_h2(ej[m_]),     a1_, false); \
        a2_ = __builtin_amdgcn_fdot2(int_as_h2(q1_), int_as_h2(ej[m_ + 1]), a2_, false); \
        a3_ = __builtin_amdgcn_fdot2(int_as_h2(q2_), int_as_h2(ej[m_ + 2]), a3_, false); \
        a4_ = __builtin_amdgcn_fdot2(int_as_h2(q3_), int_as_h2(ej[m_ + 3]), a4_, false); \
    } \
    float v_ = ((a1_ + a2_) + (a3_ + a4_)) * g_; \
    int eb_ = (__builtin_amdgcn_readfirstlane(__float_as_int(v_)) >> 23) & 0xFF; \
    C##X += eb_ - 127; \
    float scl_ = __int_as_float((254 - eb_) << 23); \
    u##X = v_ * scl_; \
    PACKD(X); \
    if (t##X == lo1##X) MEAS(X, A_in##X); \
    if (t##X == hi##X - 1) MEAS(X, A_out##X); \
    ++t##X; \
}

__global__ __launch_bounds__(256) void crf_piece_kernel(
    const float* __restrict__ logits,    // [B][T][L]
    const int*   __restrict__ labels,    // [B][T]
    const int*   __restrict__ seq_lens,  // [B]
    const float* __restrict__ trans,     // [L][L]
    const int*   __restrict__ meta,      // [258]: piece prefix, P, K
    float*       __restrict__ part)      // [NCHAIN]
{
    const int wid  = blockIdx.x * 4 + (threadIdx.x >> 6);
    const int lane = threadIdx.x & 63;
    const int P = meta[BB];
    const int K = meta[BB + 1];

    // one-time per wave, shared by both chains: E-column pairs, col j = lane
    int ej[32];
    #pragma unroll
    for (int m = 0; m < 32; ++m) {
        half2v pp;
        pp[0] = (__fp16)__builtin_amdgcn_exp2f(trans[(2 * m)     * LL + lane] * LOG2E);
        pp[1] = (__fp16)__builtin_amdgcn_exp2f(trans[(2 * m + 1) * LL + lane] * LOG2E);
        ej[m] = h2_as_int(pp);
    }

    // chain state
    const float *colA, *colB;
    int hiA, hiB, lo1A, lo1B, stepsA, stepsB, CA, CB, upkA, upkB, tA, tB;
    float uA, uB, scA, scB;
    float A_inA = 0.f, A_outA = 0.f, A_inB = 0.f, A_outB = 0.f;
    float frA0, frA1, frA2, frA3, frB0, frB1, frB2, frB3;
    bool actA, actB;
    // token-paste helpers expect names C A / u A etc. via ##
    #define CA_ CA
    SETUP(A, 2 * wid);
    SETUP(B, 2 * wid + 1);

    int N = (stepsA > stepsB) ? stepsA : stepsB;
    int nR = (N + 3) >> 2;
    for (int r_ = 0; r_ < nR; ++r_) {
        STEP1(A, 0); STEP1(B, 0);
        STEP1(A, 1); STEP1(B, 1);
        STEP1(A, 2); STEP1(B, 2);
        STEP1(A, 3); STEP1(B, 3);
    }

    float resA = actA ? ((A_outA - A_inA) - scA) : 0.f;
    float resB = actB ? ((A_outB - A_inB) - scB) : 0.f;
    if (lane == 0) {
        part[2 * wid]     = resA;
        part[2 * wid + 1] = resB;
    }
}

__global__ __launch_bounds__(1024) void reduce_kernel(
    const float* __restrict__ part, float* __restrict__ out)
{
    int tid = threadIdx.x;
    float v = 0.f;
    #pragma unroll
    for (int i = 0; i < 8; ++i) v += part[tid + 1024 * i];
    #pragma unroll
    for (int off = 32; off; off >>= 1) v += __shfl_xor(v, off, 64);
    __shared__ float r[16];
    if ((tid & 63) == 0) r[tid >> 6] = v;
    __syncthreads();
    if (tid == 0) {
        float s = 0.f;
        #pragma unroll
        for (int i = 0; i < 16; ++i) s += r[i];
        out[0] = s;
    }
}

extern "C" void kernel_launch(void* const* d_in, const int* in_sizes, int n_in,
                              void* d_out, int out_size, void* d_ws, size_t ws_size,
                              hipStream_t stream) {
    const float* logits   = (const float*)d_in[0];
    const int*   labels   = (const int*)d_in[1];
    const int*   seq_lens = (const int*)d_in[2];
    const float* trans    = (const float*)d_in[3];

    int*   meta = (int*)d_ws;                         // 258 ints (<4 KB)
    float* part = (float*)((char*)d_ws + 4096);       // NCHAIN floats (32 KB)

    crf_prefix_kernel<<<1, 256, 0, stream>>>(seq_lens, meta);
    crf_piece_kernel<<<1024, 256, 0, stream>>>(logits, labels, seq_lens, trans,
                                               meta, part);
    reduce_kernel<<<1, 1024, 0, stream>>>(part, (float*)d_out);
}